// Round 9
// baseline (90.916 us; speedup 1.0000x reference)
//
#include <hip/hip_runtime.h>

#define C_EMB 256
#define NPL   9             // points per level
#define NLV   2             // levels
#define NPTS  (NPL * NLV)   // 18
#define NJ    (NPTS * 2)    // 36 offset outputs per query

__global__ void transpose_woff(const float* __restrict__ W_off, float* __restrict__ WT) {
    // W_off: [C_EMB, NJ] -> WT: [NJ, C_EMB]
    int j = blockIdx.x;       // 0..35
    int c = threadIdx.x;      // 0..255
    WT[j * C_EMB + c] = W_off[c * NJ + j];
}

__device__ __forceinline__ int imin(int a, int b) { return a < b ? a : b; }
__device__ __forceinline__ int imax(int a, int b) { return a > b ? a : b; }

// x + dpp_select(x); masked-out/invalid lanes contribute 0 (old=0, bound_ctrl=1)
template<int CTRL, int ROW_MASK>
__device__ __forceinline__ float dpp_add(float x) {
    int t = __builtin_amdgcn_update_dpp(0, __builtin_bit_cast(int, x),
                                        CTRL, ROW_MASK, 0xf, true);
    return x + __builtin_bit_cast(float, t);
}

// Canonical GCN wave64 sum (VALU-only): row_shr 1,2,4,8 then row_bcast:15/31;
// total in lane 63, broadcast via readlane. HW-verified (rounds 3-8).
__device__ __forceinline__ float wave_sum_all(float x) {
    x = dpp_add<0x111, 0xf>(x);   // row_shr:1
    x = dpp_add<0x112, 0xf>(x);   // row_shr:2
    x = dpp_add<0x114, 0xf>(x);   // row_shr:4
    x = dpp_add<0x118, 0xf>(x);   // row_shr:8
    x = dpp_add<0x142, 0xa>(x);   // row_bcast:15 -> rows 1,3
    x = dpp_add<0x143, 0xc>(x);   // row_bcast:31 -> rows 2,3
    int r = __builtin_amdgcn_readlane(__builtin_bit_cast(int, x), 63);
    return __builtin_bit_cast(float, r);
}

// Fused kernel, one wave per query, ONLINE softmax (no kv[18] array):
// per point: gather 4 rows -> kvp -> logit wave-reduce -> flash-style
// (m, sum, o) update. kv regs freed -> compiler can hoist next-point loads.
// All value/WT loads use uniform-base + 32-bit byte offset (saddr form).
template<bool USE_WT>
__global__ __launch_bounds__(128, 3)
void deform_attn_kernel(const float* __restrict__ query,
                        const float* __restrict__ value,
                        const float* __restrict__ refp,
                        const int*   __restrict__ sshapes,
                        const float* __restrict__ WT,
                        const float* __restrict__ W_off,
                        const float* __restrict__ b_off,
                        float*       __restrict__ out,
                        int nq, int nv) {
    const int lane = threadIdx.x & 63;
    const int widx = threadIdx.x >> 6;        // 0..1
    const int q = blockIdx.x * 2 + widx;
    if (q >= nq) return;

    __shared__ int4   s_idx[2][NPTS];
    __shared__ float4 s_w[2][NPTS];

    const int coff  = lane * 4;               // float offset within row
    const unsigned coff4 = (unsigned)lane * 16u;  // byte offset within row
    const float4 q4 = *reinterpret_cast<const float4*>(query + (size_t)q * C_EMB + coff);

    // ---------------- sampling offsets: off[j] = dot(q, W_off[:,j]) + b_off[j] ----------------
    float ox = 0.f, oy = 0.f;
    const char* wtb = (const char*)WT;
    #pragma unroll
    for (int j = 0; j < NJ; ++j) {
        float s;
        if (USE_WT) {
            float4 w4 = *reinterpret_cast<const float4*>(wtb + ((unsigned)(j * 1024) + coff4));
            s = q4.x * w4.x + q4.y * w4.y + q4.z * w4.z + q4.w * w4.w;
        } else {
            const float* wp = W_off + (size_t)coff * NJ + j;
            s = q4.x * wp[0] + q4.y * wp[NJ] + q4.z * wp[2 * NJ] + q4.w * wp[3 * NJ];
        }
        s = wave_sum_all(s) + b_off[j];
        if (j == 2 * lane)     ox = s;
        if (j == 2 * lane + 1) oy = s;
    }

    // ---------------- geometry: lanes 0..17 each handle one (level, point) ----------------
    if (lane < NPTS) {
        int l = lane / NPL;
        int Hi = sshapes[l * 2 + 0];
        int Wi = sshapes[l * 2 + 1];
        float fw = (float)Wi, fh = (float)Hi;
        float rx = refp[((size_t)q * NLV + l) * 2 + 0];
        float ry = refp[((size_t)q * NLV + l) * 2 + 1];
        // x = loc*W - 0.5 ; loc = ref + off/W  ->  x = ref*W + off - 0.5
        float x = rx * fw + ox - 0.5f;
        float y = ry * fh + oy - 0.5f;
        float x0f = floorf(x), y0f = floorf(y);
        int x0 = (int)x0f, y0 = (int)y0f;
        float wx1 = x - x0f, wy1 = y - y0f;
        float wx0 = 1.f - wx1, wy0 = 1.f - wy1;
        bool vx0 = (x0 >= 0) && (x0 <= Wi - 1);
        bool vx1 = (x0 + 1 >= 0) && (x0 + 1 <= Wi - 1);
        bool vy0 = (y0 >= 0) && (y0 <= Hi - 1);
        bool vy1 = (y0 + 1 >= 0) && (y0 + 1 <= Hi - 1);
        int cx0 = imin(imax(x0, 0), Wi - 1);
        int cx1 = imin(imax(x0 + 1, 0), Wi - 1);
        int cy0 = imin(imax(y0, 0), Hi - 1);
        int cy1 = imin(imax(y0 + 1, 0), Hi - 1);
        int base = l * nv;
        int4 id;
        id.x = base + cy0 * Wi + cx0;
        id.y = base + cy0 * Wi + cx1;
        id.z = base + cy1 * Wi + cx0;
        id.w = base + cy1 * Wi + cx1;
        float4 w;
        w.x = wx0 * wy0 * ((vx0 && vy0) ? 1.f : 0.f);
        w.y = wx1 * wy0 * ((vx1 && vy0) ? 1.f : 0.f);
        w.z = wx0 * wy1 * ((vx0 && vy1) ? 1.f : 0.f);
        w.w = wx1 * wy1 * ((vx1 && vy1) ? 1.f : 0.f);
        s_idx[widx][lane] = id;
        s_w[widx][lane]   = w;
    }
    __builtin_amdgcn_wave_barrier();   // wave-local LDS producer->consumer; ds ops are wave-ordered

    // ---------------- online-softmax gather loop (no kv array) ----------------
    const char* vb = (const char*)value;
    float m = -3.0e38f, ssum = 0.f;
    float4 o; o.x = 0.f; o.y = 0.f; o.z = 0.f; o.w = 0.f;
    #pragma unroll
    for (int p = 0; p < NPTS; ++p) {
        int4   id = s_idx[widx][p];
        float4 w  = s_w[widx][p];
        const float4 a = *reinterpret_cast<const float4*>(vb + (((unsigned)id.x << 10) + coff4));
        const float4 b = *reinterpret_cast<const float4*>(vb + (((unsigned)id.y << 10) + coff4));
        const float4 c = *reinterpret_cast<const float4*>(vb + (((unsigned)id.z << 10) + coff4));
        const float4 d = *reinterpret_cast<const float4*>(vb + (((unsigned)id.w << 10) + coff4));
        float4 kvp;
        kvp.x = w.x * a.x + w.y * b.x + w.z * c.x + w.w * d.x;
        kvp.y = w.x * a.y + w.y * b.y + w.z * c.y + w.w * d.y;
        kvp.z = w.x * a.z + w.y * b.z + w.z * c.z + w.w * d.z;
        kvp.w = w.x * a.w + w.y * b.w + w.z * c.w + w.w * d.w;
        float dp = q4.x * kvp.x + q4.y * kvp.y + q4.z * kvp.z + q4.w * kvp.w;
        float lg = wave_sum_all(dp) * 16.0f;   // * sqrt(C), C=256
        float mn = fmaxf(m, lg);
        float sc = __expf(m - mn);             // first iter: exp(-inf) = 0
        float pv = __expf(lg - mn);
        ssum = ssum * sc + pv;
        o.x = o.x * sc + pv * kvp.x;
        o.y = o.y * sc + pv * kvp.y;
        o.z = o.z * sc + pv * kvp.z;
        o.w = o.w * sc + pv * kvp.w;
        m = mn;
    }
    float inv = 1.0f / ssum;
    o.x *= inv; o.y *= inv; o.z *= inv; o.w *= inv;
    *reinterpret_cast<float4*>(out + (size_t)q * C_EMB + coff) = o;
}

extern "C" void kernel_launch(void* const* d_in, const int* in_sizes, int n_in,
                              void* d_out, int out_size, void* d_ws, size_t ws_size,
                              hipStream_t stream) {
    const float* query = (const float*)d_in[0];
    // d_in[1] = key (unused by forward)
    const float* value = (const float*)d_in[2];
    const float* refp  = (const float*)d_in[3];
    const int*   ss    = (const int*)d_in[4];
    const float* W_off = (const float*)d_in[5];
    const float* b_off = (const float*)d_in[6];
    float* out = (float*)d_out;

    const int nq = in_sizes[0] / C_EMB;          // 20000
    const int nl = in_sizes[4] / 2;              // 2
    const int nv = in_sizes[2] / (nl * C_EMB);   // 16384

    const int blocks = (nq + 1) / 2;             // 2 single-wave queries per block

    const size_t wt_bytes = (size_t)NJ * C_EMB * sizeof(float);
    if (ws_size >= wt_bytes) {
        float* WT = (float*)d_ws;
        transpose_woff<<<NJ, C_EMB, 0, stream>>>(W_off, WT);
        deform_attn_kernel<true><<<blocks, 128, 0, stream>>>(
            query, value, refp, ss, WT, W_off, b_off, out, nq, nv);
    } else {
        deform_attn_kernel<false><<<blocks, 128, 0, stream>>>(
            query, value, refp, ss, nullptr, W_off, b_off, out, nq, nv);
    }
}